// Round 1
// baseline (197.937 us; speedup 1.0000x reference)
//
#include <hip/hip_runtime.h>
#include <hip/hip_bf16.h>
#include <stdint.h>

#define BATCH    512
#define IN_DIM   256
#define OUT_DIM  256
#define COND_DIM 128
#define HIDDEN   128
#define W2_COLS  65792      // 256*257 = IO + OUT_DIM
#define NPLANES  130        // 128 h-planes + b2-plane + base_weight-plane
#define H_STRIDE 130

typedef __attribute__((ext_vector_type(8))) short bf16x8;
typedef __attribute__((ext_vector_type(4))) float f32x4;

// h_ext[b][p]: p<128 -> relu(cond@w1+b1), p=128,129 -> 1.0f
__device__ float g_h[BATCH * H_STRIDE];

static __device__ __forceinline__ unsigned short f2bf(float f) {
    union { float f; unsigned int u; } v; v.f = f;
    unsigned int r = v.u + 0x7FFFu + ((v.u >> 16) & 1u);  // RNE
    return (unsigned short)(r >> 16);
}
static __device__ __forceinline__ unsigned int pack2(float a, float b) {
    return (unsigned int)f2bf(a) | ((unsigned int)f2bf(b) << 16);
}

// ---------------- kernel A: h = relu(cond @ w1 + b1), plus ones planes ----
__global__ void hyper_h_kernel(const float* __restrict__ cond,
                               const float* __restrict__ w1,
                               const float* __restrict__ b1) {
    __shared__ float c[COND_DIM];
    int b = blockIdx.x;
    int k = threadIdx.x;           // 128 threads
    c[k] = cond[b * COND_DIM + k];
    __syncthreads();
    float acc = b1[k];
    #pragma unroll 8
    for (int i = 0; i < COND_DIM; ++i)
        acc += c[i] * w1[i * HIDDEN + k];
    g_h[b * H_STRIDE + k] = fmaxf(acc, 0.0f);
    if (k < 2) g_h[b * H_STRIDE + 128 + k] = 1.0f;
}

// ---------------- kernel B: init out with bias terms ----------------------
// out[b,o] = base_bias[o] + b2[65536+o] + sum_k h[b,k]*w2[k,65536+o]
__global__ void hyper_bias_kernel(const float* __restrict__ base_bias,
                                  const float* __restrict__ w2,
                                  const float* __restrict__ b2,
                                  float* __restrict__ out) {
    int o  = threadIdx.x;          // 256
    int b0 = blockIdx.x * 8;       // 64 blocks x 8 batches
    float base = base_bias[o] + b2[65536 + o];
    float acc[8];
    #pragma unroll
    for (int j = 0; j < 8; ++j) acc[j] = base;
    for (int k = 0; k < HIDDEN; ++k) {
        float w = w2[(size_t)k * W2_COLS + 65536 + o];
        #pragma unroll
        for (int j = 0; j < 8; ++j)
            acc[j] += g_h[(b0 + j) * H_STRIDE + k] * w;
    }
    #pragma unroll
    for (int j = 0; j < 8; ++j) out[(b0 + j) * OUT_DIM + o] = acc[j];
}

// ---------------- kernel C: main split-K MFMA GEMM ------------------------
// out[b,o] += sum_{p,i} hext[b,p] * x[b,i] * planebase_p[i*256+o]
#define BM 128
#define BN 64
#define PLANES_PER_CHUNK 5
#define NCHUNKS 26            // 130 / 5
#define ASTRIDE 72            // bf16 elems per A_lds row (pad 64+8, 144B div 16)
#define BSTRIDE 68            // bf16 elems per B_lds row (pad 64+4)

__global__ __launch_bounds__(256)
void hyper_main_kernel(const float* __restrict__ x,
                       const float* __restrict__ base_weight,
                       const float* __restrict__ w2,
                       const float* __restrict__ b2,
                       float* __restrict__ out) {
    __shared__ __align__(16) unsigned short A_lds[BM * ASTRIDE];
    __shared__ __align__(16) unsigned short B_lds[64 * BSTRIDE];

    int bx    = blockIdx.x;               // 416 = 26 chunks * 4 mt * 4 nt
    int chunk = bx >> 4;
    int rem   = bx & 15;
    int mt    = rem >> 2;
    int nt    = rem & 3;
    int b0    = mt * BM;
    int o0    = nt * BN;

    int t    = threadIdx.x;               // 256 threads = 4 waves
    int lane = t & 63;
    int wave = t >> 6;                    // n-strip: cols o0 + wave*16 + ncol
    int qg   = lane >> 4;                 // 0..3
    int ncol = lane & 15;

    // staging maps
    int abl   = t >> 1;                   // A: batch-row 0..127
    int ahalf = t & 1;                    // A: half of 64 i's
    int bcg   = t & 15;                   // B: col group (4 floats)
    int brow0 = t >> 4;                   // B: row 0..15 (+q*16)

    f32x4 acc[8];
    #pragma unroll
    for (int mf = 0; mf < 8; ++mf) acc[mf] = (f32x4){0.f, 0.f, 0.f, 0.f};

    const int p_base = chunk * PLANES_PER_CHUNK;

    for (int s = 0; s < PLANES_PER_CHUNK * 4; ++s) {
        int p  = p_base + (s >> 2);
        int i0 = (s & 3) * 64;
        const float* pb = (p < 128) ? (w2 + (size_t)p * W2_COLS)
                                    : (p == 128 ? b2 : base_weight);

        // ---- stage A: A_lds[b][i_local] = x[b0+b, i0+i_local] * hext[b0+b, p]
        {
            float hs = g_h[(b0 + abl) * H_STRIDE + p];
            const float4* xs = (const float4*)(x + (size_t)(b0 + abl) * IN_DIM + i0 + ahalf * 32);
            unsigned int* adst = (unsigned int*)&A_lds[abl * ASTRIDE + ahalf * 32];
            #pragma unroll
            for (int q = 0; q < 8; ++q) {
                float4 v = xs[q];
                adst[q * 2]     = pack2(v.x * hs, v.y * hs);
                adst[q * 2 + 1] = pack2(v.z * hs, v.w * hs);
            }
        }
        // ---- stage B: B_lds[r][o_local] = pb[(i0+r)*256 + o0 + o_local]
        {
            #pragma unroll
            for (int q = 0; q < 4; ++q) {
                int row = brow0 + q * 16;
                const float4* src = (const float4*)(pb + (size_t)(i0 + row) * OUT_DIM + o0 + bcg * 4);
                float4 v = *src;
                unsigned int* bdst = (unsigned int*)&B_lds[row * BSTRIDE + bcg * 4];
                bdst[0] = pack2(v.x, v.y);
                bdst[1] = pack2(v.z, v.w);
            }
        }
        __syncthreads();

        // ---- MFMA: 2 k-steps of 32
        #pragma unroll
        for (int ks = 0; ks < 2; ++ks) {
            int k0 = ks * 32;
            bf16x8 bfrag;
            #pragma unroll
            for (int j = 0; j < 8; ++j)
                bfrag[j] = (short)B_lds[(k0 + qg * 8 + j) * BSTRIDE + wave * 16 + ncol];
            #pragma unroll
            for (int mf = 0; mf < 8; ++mf) {
                const bf16x8* ap = (const bf16x8*)(const void*)
                    &A_lds[(mf * 16 + ncol) * ASTRIDE + k0 + qg * 8];
                acc[mf] = __builtin_amdgcn_mfma_f32_16x16x32_bf16(*ap, bfrag, acc[mf], 0, 0, 0);
            }
        }
        __syncthreads();
    }

    // ---- epilogue: atomic accumulate (C/D layout: col=lane&15, row=qg*4+reg)
    #pragma unroll
    for (int mf = 0; mf < 8; ++mf) {
        #pragma unroll
        for (int reg = 0; reg < 4; ++reg) {
            int row = b0 + mf * 16 + qg * 4 + reg;
            int col = o0 + wave * 16 + ncol;
            atomicAdd(&out[(size_t)row * OUT_DIM + col], acc[mf][reg]);
        }
    }
}

// ---------------- launch ---------------------------------------------------
extern "C" void kernel_launch(void* const* d_in, const int* in_sizes, int n_in,
                              void* d_out, int out_size, void* d_ws, size_t ws_size,
                              hipStream_t stream) {
    const float* x           = (const float*)d_in[0];
    const float* cond        = (const float*)d_in[1];
    const float* base_weight = (const float*)d_in[2];
    const float* base_bias   = (const float*)d_in[3];
    const float* w1          = (const float*)d_in[4];
    const float* b1          = (const float*)d_in[5];
    const float* w2          = (const float*)d_in[6];
    const float* b2          = (const float*)d_in[7];
    float* out = (float*)d_out;

    hyper_h_kernel<<<BATCH, COND_DIM, 0, stream>>>(cond, w1, b1);
    hyper_bias_kernel<<<BATCH / 8, OUT_DIM, 0, stream>>>(base_bias, w2, b2, out);
    hyper_main_kernel<<<NCHUNKS * 16, 256, 0, stream>>>(x, base_weight, w2, b2, out);
}

// Round 2
// 166.548 us; speedup vs baseline: 1.1885x; 1.1885x over previous
//
#include <hip/hip_runtime.h>
#include <hip/hip_bf16.h>
#include <stdint.h>

#define BATCH    512
#define IN_DIM   256
#define OUT_DIM  256
#define COND_DIM 128
#define HIDDEN   128
#define W2_COLS  65792      // 256*257 = IO + OUT_DIM
#define H_STRIDE 130
#define NCHUNK   65         // 2 planes per chunk, 130 planes total
#define NSTAGE   8          // 2 planes * 4 i-chunks of 64
#define OUT_ELEMS (BATCH * OUT_DIM)          // 131072
#define WS_NEEDED ((size_t)(NCHUNK + 1) * OUT_ELEMS * 4)

typedef __attribute__((ext_vector_type(8))) short bf16x8;
typedef __attribute__((ext_vector_type(4))) float f32x4;

// h_ext[b][p]: p<128 -> relu(cond@w1+b1), p=128,129 -> 1.0f
__device__ float g_h[BATCH * H_STRIDE];

static __device__ __forceinline__ unsigned short f2bf(float f) {
    union { float f; unsigned int u; } v; v.f = f;
    unsigned int r = v.u + 0x7FFFu + ((v.u >> 16) & 1u);  // RNE
    return (unsigned short)(r >> 16);
}
static __device__ __forceinline__ unsigned int pack2(float a, float b) {
    return (unsigned int)f2bf(a) | ((unsigned int)f2bf(b) << 16);
}

// ---------------- kernel A: h = relu(cond @ w1 + b1), plus ones planes ----
__global__ void hyper_h_kernel(const float* __restrict__ cond,
                               const float* __restrict__ w1,
                               const float* __restrict__ b1) {
    __shared__ float c[COND_DIM];
    int b = blockIdx.x;
    int k = threadIdx.x;           // 128 threads
    c[k] = cond[b * COND_DIM + k];
    __syncthreads();
    float acc = b1[k];
    #pragma unroll 8
    for (int i = 0; i < COND_DIM; ++i)
        acc += c[i] * w1[i * HIDDEN + k];
    g_h[b * H_STRIDE + k] = fmaxf(acc, 0.0f);
    if (k < 2) g_h[b * H_STRIDE + 128 + k] = 1.0f;
}

// ---------------- kernel B: bias terms -----------------------------------
// dst[b*256+o] = base_bias[o] + b2[65536+o] + sum_k h[b,k]*w2[k,65536+o]
__global__ void hyper_bias_kernel(const float* __restrict__ base_bias,
                                  const float* __restrict__ w2,
                                  const float* __restrict__ b2,
                                  float* __restrict__ dst) {
    int o  = threadIdx.x;          // 256
    int b0 = blockIdx.x * 8;       // 64 blocks x 8 batches
    float base = base_bias[o] + b2[65536 + o];
    float acc[8];
    #pragma unroll
    for (int j = 0; j < 8; ++j) acc[j] = base;
    for (int k = 0; k < HIDDEN; ++k) {
        float w = w2[(size_t)k * W2_COLS + 65536 + o];
        #pragma unroll
        for (int j = 0; j < 8; ++j)
            acc[j] += g_h[(b0 + j) * H_STRIDE + k] * w;
    }
    #pragma unroll
    for (int j = 0; j < 8; ++j) dst[(b0 + j) * OUT_DIM + o] = acc[j];
}

// ---------------- kernel C: main split-K MFMA GEMM ------------------------
// partial[chunk][b,o] = sum_{p in chunk, i} hext[b,p]*x[b,i]*plane_p[i*256+o]
// BM=64 rows, BN=64 cols per block; 65 chunks * 8 mt * 4 nt = 2080 blocks.
#define ASTRIDE 72            // bf16 elems per A_lds row (64 + 8 pad)
#define BSTRIDE 68            // bf16 elems per B_lds row (64 + 4 pad)

template<bool ATOMIC>
__global__ __launch_bounds__(256, 4)
void hyper_main_kernel(const float* __restrict__ x,
                       const float* __restrict__ base_weight,
                       const float* __restrict__ w2,
                       const float* __restrict__ b2,
                       float* __restrict__ dst) {
    __shared__ __align__(16) unsigned short A_lds[2][64 * ASTRIDE];  // 18.4 KB
    __shared__ __align__(16) unsigned short B_lds[2][64 * BSTRIDE];  // 17.4 KB

    const int bx    = blockIdx.x;
    const int chunk = bx >> 5;
    const int rem   = bx & 31;
    const int b0    = (rem >> 2) * 64;
    const int o0    = (rem & 3) * 64;

    const int t    = threadIdx.x;          // 256 = 4 waves
    const int lane = t & 63;
    const int wave = t >> 6;               // cols o0 + wave*16
    const int qg   = lane >> 4;
    const int ncol = lane & 15;

    const int ab = t >> 2, aq = t & 3;     // A staging: batch row, i-quarter
    const int br = t >> 4, bc = t & 15;    // B staging: row base, col group

    f32x4 acc[4];
    #pragma unroll
    for (int mf = 0; mf < 4; ++mf) acc[mf] = (f32x4){0.f, 0.f, 0.f, 0.f};

    const int p_base = chunk * 2;

    float4 pa[4]; float phs; float4 pbv[4];

    auto issue = [&](int s) {
        int p  = p_base + (s >> 2);
        int i0 = (s & 3) * 64;
        const float* pb = (p < 128) ? (w2 + (size_t)p * W2_COLS)
                                    : (p == 128 ? b2 : base_weight);
        const float* xs = x + (size_t)(b0 + ab) * IN_DIM + i0 + aq * 16;
        #pragma unroll
        for (int q = 0; q < 4; ++q) pa[q] = ((const float4*)xs)[q];
        phs = g_h[(b0 + ab) * H_STRIDE + p];
        #pragma unroll
        for (int q = 0; q < 4; ++q)
            pbv[q] = *(const float4*)(pb + (size_t)(i0 + br + q * 16) * OUT_DIM + o0 + bc * 4);
    };
    auto commit = [&](int buf) {
        unsigned int* adst = (unsigned int*)&A_lds[buf][ab * ASTRIDE + aq * 16];
        #pragma unroll
        for (int q = 0; q < 4; ++q) {
            adst[q * 2]     = pack2(pa[q].x * phs, pa[q].y * phs);
            adst[q * 2 + 1] = pack2(pa[q].z * phs, pa[q].w * phs);
        }
        #pragma unroll
        for (int q = 0; q < 4; ++q) {
            unsigned int* bdst = (unsigned int*)&B_lds[buf][(br + q * 16) * BSTRIDE + bc * 4];
            bdst[0] = pack2(pbv[q].x, pbv[q].y);
            bdst[1] = pack2(pbv[q].z, pbv[q].w);
        }
    };

    issue(0);
    commit(0);
    __syncthreads();

    for (int s = 0; s < NSTAGE; ++s) {
        const int cur = s & 1;
        if (s + 1 < NSTAGE) issue(s + 1);        // global -> regs, early

        #pragma unroll
        for (int ks = 0; ks < 2; ++ks) {
            bf16x8 bfrag;
            #pragma unroll
            for (int j = 0; j < 8; ++j)
                bfrag[j] = (short)B_lds[cur][(ks * 32 + qg * 8 + j) * BSTRIDE + wave * 16 + ncol];
            #pragma unroll
            for (int mf = 0; mf < 4; ++mf) {
                const bf16x8* ap = (const bf16x8*)(const void*)
                    &A_lds[cur][(mf * 16 + ncol) * ASTRIDE + ks * 32 + qg * 8];
                acc[mf] = __builtin_amdgcn_mfma_f32_16x16x32_bf16(*ap, bfrag, acc[mf], 0, 0, 0);
            }
        }

        if (s + 1 < NSTAGE) commit(1 - cur);     // pack + LDS write, late
        __syncthreads();
    }

    // epilogue: C/D layout col=lane&15, row=qg*4+reg
    if (ATOMIC) {
        #pragma unroll
        for (int mf = 0; mf < 4; ++mf)
            #pragma unroll
            for (int reg = 0; reg < 4; ++reg) {
                int row = b0 + mf * 16 + qg * 4 + reg;
                int col = o0 + wave * 16 + ncol;
                atomicAdd(&dst[(size_t)row * OUT_DIM + col], acc[mf][reg]);
            }
    } else {
        float* slice = dst + (size_t)chunk * OUT_ELEMS;
        #pragma unroll
        for (int mf = 0; mf < 4; ++mf)
            #pragma unroll
            for (int reg = 0; reg < 4; ++reg) {
                int row = b0 + mf * 16 + qg * 4 + reg;
                int col = o0 + wave * 16 + ncol;
                slice[(size_t)row * OUT_DIM + col] = acc[mf][reg];
            }
    }
}

// ---------------- kernel D: reduce partials -------------------------------
__global__ void hyper_reduce_kernel(const float* __restrict__ ws,
                                    float* __restrict__ out) {
    int i = blockIdx.x * 256 + threadIdx.x;        // float4 index, 32768 total
    const float4* w4 = (const float4*)ws;
    float4 a = w4[i];
    #pragma unroll 6
    for (int c = 1; c <= NCHUNK; ++c) {            // 66 slices (65 chunks + bias)
        float4 v = w4[(size_t)c * (OUT_ELEMS / 4) + i];
        a.x += v.x; a.y += v.y; a.z += v.z; a.w += v.w;
    }
    ((float4*)out)[i] = a;
}

// ---------------- launch ---------------------------------------------------
extern "C" void kernel_launch(void* const* d_in, const int* in_sizes, int n_in,
                              void* d_out, int out_size, void* d_ws, size_t ws_size,
                              hipStream_t stream) {
    const float* x           = (const float*)d_in[0];
    const float* cond        = (const float*)d_in[1];
    const float* base_weight = (const float*)d_in[2];
    const float* base_bias   = (const float*)d_in[3];
    const float* w1          = (const float*)d_in[4];
    const float* b1          = (const float*)d_in[5];
    const float* w2          = (const float*)d_in[6];
    const float* b2          = (const float*)d_in[7];
    float* out = (float*)d_out;
    float* ws  = (float*)d_ws;

    hyper_h_kernel<<<BATCH, COND_DIM, 0, stream>>>(cond, w1, b1);

    if (ws_size >= WS_NEEDED) {
        // partials path: no atomics
        hyper_bias_kernel<<<BATCH / 8, OUT_DIM, 0, stream>>>(
            base_bias, w2, b2, ws + (size_t)NCHUNK * OUT_ELEMS);
        hyper_main_kernel<false><<<NCHUNK * 32, 256, 0, stream>>>(
            x, base_weight, w2, b2, ws);
        hyper_reduce_kernel<<<OUT_ELEMS / 4 / 256, 256, 0, stream>>>(ws, out);
    } else {
        // fallback: init out with bias terms, atomically accumulate
        hyper_bias_kernel<<<BATCH / 8, OUT_DIM, 0, stream>>>(base_bias, w2, b2, out);
        hyper_main_kernel<true><<<NCHUNK * 32, 256, 0, stream>>>(
            x, base_weight, w2, b2, out);
    }
}

// Round 3
// 130.223 us; speedup vs baseline: 1.5200x; 1.2789x over previous
//
#include <hip/hip_runtime.h>
#include <hip/hip_bf16.h>
#include <stdint.h>

#define BATCH    512
#define IN_DIM   256
#define OUT_DIM  256
#define COND_DIM 128
#define HIDDEN   128
#define W2_COLS  65792      // 256*257
#define H_STRIDE 132        // padded so g_h rows are 16B-aligned for float4
#define NCHUNKS  34         // 32 chunks x 4 planes + {b2,base_weight} chunk + bias chunk
#define OUT_ELEMS (BATCH * OUT_DIM)          // 131072
#define WS_NEEDED ((size_t)NCHUNKS * OUT_ELEMS * 2)   // bf16 slices, ~8.9 MB

typedef __attribute__((ext_vector_type(8))) short bf16x8;
typedef __attribute__((ext_vector_type(4))) float f32x4;

// h_ext[b][p]: p<128 -> relu(cond@w1+b1), p=128..131 -> 1.0f
__device__ float g_h[BATCH * H_STRIDE];

static __device__ __forceinline__ unsigned short f2bf(float f) {
    union { float f; unsigned int u; } v; v.f = f;
    unsigned int r = v.u + 0x7FFFu + ((v.u >> 16) & 1u);  // RNE
    return (unsigned short)(r >> 16);
}
static __device__ __forceinline__ unsigned int pack2(float a, float b) {
    return (unsigned int)f2bf(a) | ((unsigned int)f2bf(b) << 16);
}
static __device__ __forceinline__ float bf2f(unsigned short u) {
    union { unsigned int u; float f; } v; v.u = ((unsigned int)u) << 16;
    return v.f;
}

// ---------------- kernel A: h = relu(cond @ w1 + b1), plus ones planes ----
__global__ void hyper_h_kernel(const float* __restrict__ cond,
                               const float* __restrict__ w1,
                               const float* __restrict__ b1) {
    __shared__ float c[COND_DIM];
    int b = blockIdx.x;
    int k = threadIdx.x;           // 128 threads
    c[k] = cond[b * COND_DIM + k];
    __syncthreads();
    float acc = b1[k];
    #pragma unroll 8
    for (int i = 0; i < COND_DIM; ++i)
        acc += c[i] * w1[i * HIDDEN + k];
    g_h[b * H_STRIDE + k] = fmaxf(acc, 0.0f);
    if (k < 4) g_h[b * H_STRIDE + 128 + k] = 1.0f;
}

// ---------------- kernel C: main split-K MFMA GEMM ------------------------
// chunk < 32 : 4 planes (p = chunk*4 ..), 16 stages of (plane, 64-i-slab)
// chunk == 32: planes 128 (b2), 129 (base_weight), 8 stages
// chunk == 33: bias GEMM  h(512x128) @ w2[:,65536:], 2 stages of 64 k
// Each block: 64x64 output tile; slices stored bf16 in ws.
// LDS layout: tile stored as 64 rows x 8 units(16B); unit index = row*8 + (kg ^ (row&7))
__global__ __launch_bounds__(256, 4)
void hyper_main_kernel(const float* __restrict__ x,
                       const float* __restrict__ base_weight,
                       const float* __restrict__ w2,
                       const float* __restrict__ b2,
                       unsigned short* __restrict__ ws) {
    __shared__ __align__(16) unsigned short A_lds[2][4096];   // 8 KB each buf
    __shared__ __align__(16) unsigned short B_lds[2][4096];

    const int bx    = blockIdx.x;            // 34 * 32
    const int chunk = bx >> 5;
    const int rem   = bx & 31;
    const int b0    = (rem >> 2) * 64;
    const int o0    = (rem & 3) * 64;
    const bool is_bias = (chunk == 33);
    const int nstage   = (chunk < 32) ? 16 : (chunk == 32 ? 8 : 2);
    const int p_base   = chunk * 4;

    const int t    = threadIdx.x;            // 256 = 4 waves, 2x2 wave grid
    const int lane = t & 63;
    const int wave = t >> 6;
    const int wm   = wave >> 1, wn = wave & 1;
    const int qg   = lane >> 4, ncol = lane & 15;

    const int ab = t >> 2, aq = t & 3;       // A staging: row, k-quarter(16)
    const int np = (t & 31) * 2, kq = t >> 5;// B staging: col pair, k-octet

    f32x4 acc[2][2];
    #pragma unroll
    for (int i = 0; i < 2; ++i)
        #pragma unroll
        for (int j = 0; j < 2; ++j) acc[i][j] = (f32x4){0.f, 0.f, 0.f, 0.f};

    float4 pa[4]; float phs; float2 pbv[8];

    auto issue = [&](int s) {
        if (!is_bias) {
            int p  = p_base + (s >> 2);
            int i0 = (s & 3) * 64;
            const float* pb = (p < 128) ? (w2 + (size_t)p * W2_COLS)
                                        : (p == 128 ? b2 : base_weight);
            phs = g_h[(b0 + ab) * H_STRIDE + p];
            const float4* xs = (const float4*)(x + (size_t)(b0 + ab) * IN_DIM + i0 + aq * 16);
            #pragma unroll
            for (int q = 0; q < 4; ++q) pa[q] = xs[q];
            const float* bb = pb + (size_t)(i0 + kq * 8) * OUT_DIM + o0 + np;
            #pragma unroll
            for (int j = 0; j < 8; ++j)
                pbv[j] = *(const float2*)(bb + (size_t)j * OUT_DIM);
        } else {
            int k0 = s * 64;
            phs = 1.0f;
            const float4* hs = (const float4*)(g_h + (size_t)(b0 + ab) * H_STRIDE + k0 + aq * 16);
            #pragma unroll
            for (int q = 0; q < 4; ++q) pa[q] = hs[q];
            const float* bb = w2 + 65536 + (size_t)(k0 + kq * 8) * W2_COLS + o0 + np;
            #pragma unroll
            for (int j = 0; j < 8; ++j)
                pbv[j] = *(const float2*)(bb + (size_t)j * W2_COLS);
        }
    };
    auto commit = [&](int buf) {
        // A: 16 consecutive k (aq*16..) of row ab -> units kg=aq*2, aq*2+1
        uint4 u0, u1;
        u0.x = pack2(pa[0].x * phs, pa[0].y * phs);
        u0.y = pack2(pa[0].z * phs, pa[0].w * phs);
        u0.z = pack2(pa[1].x * phs, pa[1].y * phs);
        u0.w = pack2(pa[1].z * phs, pa[1].w * phs);
        u1.x = pack2(pa[2].x * phs, pa[2].y * phs);
        u1.y = pack2(pa[2].z * phs, pa[2].w * phs);
        u1.z = pack2(pa[3].x * phs, pa[3].y * phs);
        u1.w = pack2(pa[3].z * phs, pa[3].w * phs);
        int sw = ab & 7;
        *(uint4*)&A_lds[buf][(ab * 8 + ((aq * 2)     ^ sw)) * 8] = u0;
        *(uint4*)&A_lds[buf][(ab * 8 + ((aq * 2 + 1) ^ sw)) * 8] = u1;
        // B transposed: rows n=np, np+1; unit kg=kq holds k = kq*8..+7
        uint4 v0, v1;
        v0.x = pack2(pbv[0].x, pbv[1].x); v0.y = pack2(pbv[2].x, pbv[3].x);
        v0.z = pack2(pbv[4].x, pbv[5].x); v0.w = pack2(pbv[6].x, pbv[7].x);
        v1.x = pack2(pbv[0].y, pbv[1].y); v1.y = pack2(pbv[2].y, pbv[3].y);
        v1.z = pack2(pbv[4].y, pbv[5].y); v1.w = pack2(pbv[6].y, pbv[7].y);
        *(uint4*)&B_lds[buf][( np      * 8 + (kq ^ ( np      & 7))) * 8] = v0;
        *(uint4*)&B_lds[buf][((np + 1) * 8 + (kq ^ ((np + 1) & 7))) * 8] = v1;
    };

    issue(0);
    commit(0);
    __syncthreads();

    for (int s = 0; s < nstage; ++s) {
        const int cur = s & 1;
        if (s + 1 < nstage) issue(s + 1);    // global -> regs, overlaps MFMA

        #pragma unroll
        for (int ks = 0; ks < 2; ++ks) {
            const int kg = ks * 4 + qg;
            bf16x8 af[2], bfr[2];
            #pragma unroll
            for (int mf = 0; mf < 2; ++mf) {
                int m = wm * 32 + mf * 16 + ncol;
                af[mf] = *(const bf16x8*)&A_lds[cur][(m * 8 + (kg ^ (m & 7))) * 8];
            }
            #pragma unroll
            for (int nf = 0; nf < 2; ++nf) {
                int n = wn * 32 + nf * 16 + ncol;
                bfr[nf] = *(const bf16x8*)&B_lds[cur][(n * 8 + (kg ^ (n & 7))) * 8];
            }
            #pragma unroll
            for (int mf = 0; mf < 2; ++mf)
                #pragma unroll
                for (int nf = 0; nf < 2; ++nf)
                    acc[mf][nf] = __builtin_amdgcn_mfma_f32_16x16x32_bf16(
                        af[mf], bfr[nf], acc[mf][nf], 0, 0, 0);
        }

        if (s + 1 < nstage) commit(1 - cur);
        __syncthreads();
    }

    // epilogue: bf16 slice store. C/D layout: col=lane&15, row=qg*4+reg
    unsigned short* slice = ws + (size_t)chunk * OUT_ELEMS;
    #pragma unroll
    for (int mf = 0; mf < 2; ++mf)
        #pragma unroll
        for (int nf = 0; nf < 2; ++nf)
            #pragma unroll
            for (int reg = 0; reg < 4; ++reg) {
                int row = b0 + wm * 32 + mf * 16 + qg * 4 + reg;
                int col = o0 + wn * 32 + nf * 16 + ncol;
                slice[(size_t)row * OUT_DIM + col] = f2bf(acc[mf][nf][reg]);
            }
}

// ---------------- kernel D: reduce bf16 slices + bias vectors -------------
__global__ void hyper_reduce_kernel(const unsigned short* __restrict__ ws,
                                    const float* __restrict__ base_bias,
                                    const float* __restrict__ b2,
                                    float* __restrict__ out) {
    int i = blockIdx.x * 256 + threadIdx.x;        // float4 index, 32768 total
    int o = (i & 63) * 4;
    float4 bb = *(const float4*)(base_bias + o);
    float4 c2 = *(const float4*)(b2 + 65536 + o);
    float4 a;
    a.x = bb.x + c2.x; a.y = bb.y + c2.y; a.z = bb.z + c2.z; a.w = bb.w + c2.w;
    #pragma unroll
    for (int c = 0; c < NCHUNKS; ++c) {
        ushort4 v = *(const ushort4*)(ws + (size_t)c * OUT_ELEMS + (size_t)i * 4);
        a.x += bf2f(v.x); a.y += bf2f(v.y); a.z += bf2f(v.z); a.w += bf2f(v.w);
    }
    ((float4*)out)[i] = a;
}

// ---------------- launch ---------------------------------------------------
extern "C" void kernel_launch(void* const* d_in, const int* in_sizes, int n_in,
                              void* d_out, int out_size, void* d_ws, size_t ws_size,
                              hipStream_t stream) {
    const float* x           = (const float*)d_in[0];
    const float* cond        = (const float*)d_in[1];
    const float* base_weight = (const float*)d_in[2];
    const float* base_bias   = (const float*)d_in[3];
    const float* w1          = (const float*)d_in[4];
    const float* b1          = (const float*)d_in[5];
    const float* w2          = (const float*)d_in[6];
    const float* b2          = (const float*)d_in[7];
    float* out = (float*)d_out;
    unsigned short* ws = (unsigned short*)d_ws;

    hyper_h_kernel<<<BATCH, COND_DIM, 0, stream>>>(cond, w1, b1);
    hyper_main_kernel<<<NCHUNKS * 32, 256, 0, stream>>>(x, base_weight, w2, b2, ws);
    hyper_reduce_kernel<<<OUT_ELEMS / 4 / 256, 256, 0, stream>>>(ws, base_bias, b2, out);
}

// Round 4
// 123.803 us; speedup vs baseline: 1.5988x; 1.0519x over previous
//
#include <hip/hip_runtime.h>
#include <hip/hip_bf16.h>
#include <stdint.h>

#define BATCH    512
#define IN_DIM   256
#define OUT_DIM  256
#define COND_DIM 128
#define HIDDEN   128
#define W2_COLS  65792      // 256*257
#define H_STRIDE 132
#define PLANE_SZ 65536      // shorts per transposed bf16 plane [o][i]
#define NCHUNKS  34         // 32x4-plane + {b2,bw} + bias
#define OUT_ELEMS (BATCH * OUT_DIM)
#define SLICE_OFF ((size_t)131 * PLANE_SZ)   // shorts: slices after 131 planes

typedef __attribute__((ext_vector_type(8))) short bf16x8;
typedef __attribute__((ext_vector_type(4))) float f32x4;

__device__ float          g_h[BATCH * H_STRIDE + 8];   // f32 h (+1.0 planes), padded
__device__ unsigned short g_hbf[BATCH * HIDDEN];       // bf16 h for bias-chunk A frags
__device__ unsigned short g_xbf[BATCH * IN_DIM];       // bf16 x for A frags

static __device__ __forceinline__ unsigned short f2bf(float f) {
    union { float f; unsigned int u; } v; v.f = f;
    unsigned int r = v.u + 0x7FFFu + ((v.u >> 16) & 1u);  // RNE
    return (unsigned short)(r >> 16);
}
static __device__ __forceinline__ unsigned int pack2(float a, float b) {
    return (unsigned int)f2bf(a) | ((unsigned int)f2bf(b) << 16);
}
static __device__ __forceinline__ float bf2f(unsigned short u) {
    union { unsigned int u; float f; } v; v.u = ((unsigned int)u) << 16;
    return v.f;
}

// ---------------- prep: convert/transpose planes + x,h ---------------------
// grid: [0,2080) w2/b2/bw plane tiles; [2080,2088) bias-col tiles;
//       [2088,2104) x convert; [2104,2360) h compute (2 rows/block)
__global__ __launch_bounds__(256)
void hyper_prep_kernel(const float* __restrict__ x,
                       const float* __restrict__ cond,
                       const float* __restrict__ base_weight,
                       const float* __restrict__ w1,
                       const float* __restrict__ b1,
                       const float* __restrict__ w2,
                       const float* __restrict__ b2,
                       unsigned short* __restrict__ wt) {
    const int bx = blockIdx.x;
    const int t  = threadIdx.x;
    if (bx < 2088) {
        int p, it, ot; const float* src; int rstride;
        if (bx < 2080) {
            p = bx >> 4; int sub = bx & 15; it = sub >> 2; ot = sub & 3;
            src = (p < 128) ? (w2 + (size_t)p * W2_COLS) : (p == 128 ? b2 : base_weight);
            rstride = OUT_DIM;
        } else {
            p = 130; int sub = bx - 2080; it = sub >> 2; ot = sub & 3;   // it 0..1 (k<128)
            src = w2 + 65536; rstride = W2_COLS;
        }
        int o  = ot * 64 + (t & 63);
        int i0 = it * 64 + (t >> 6) * 16;
        unsigned int vv[8];
        #pragma unroll
        for (int r = 0; r < 8; ++r) {
            float a = src[(size_t)(i0 + 2 * r)     * rstride + o];
            float b = src[(size_t)(i0 + 2 * r + 1) * rstride + o];
            vv[r] = pack2(a, b);
        }
        unsigned int* dst = (unsigned int*)(wt + (size_t)p * PLANE_SZ + (size_t)o * 256 + i0);
        *(uint4*)dst       = *(uint4*)&vv[0];
        *(uint4*)(dst + 4) = *(uint4*)&vv[4];
    } else if (bx < 2104) {
        int base = (bx - 2088) * 8192 + t * 32;
        #pragma unroll
        for (int g = 0; g < 4; ++g) {
            const float4* s4 = (const float4*)(x + base + g * 8);
            float4 a = s4[0], b = s4[1];
            unsigned int vv[4] = { pack2(a.x, a.y), pack2(a.z, a.w),
                                   pack2(b.x, b.y), pack2(b.z, b.w) };
            *(uint4*)(g_xbf + base + g * 8) = *(uint4*)vv;
        }
    } else {
        __shared__ float c[2][COND_DIM];
        int bb = t >> 7, k = t & 127;
        int b  = (bx - 2104) * 2 + bb;
        c[bb][k] = cond[b * COND_DIM + k];
        __syncthreads();
        float acc = b1[k];
        #pragma unroll 8
        for (int i = 0; i < COND_DIM; ++i)
            acc += c[bb][i] * w1[i * HIDDEN + k];
        acc = fmaxf(acc, 0.0f);
        g_h[b * H_STRIDE + k] = acc;
        g_hbf[b * HIDDEN + k] = f2bf(acc);
        if (k < 4) g_h[b * H_STRIDE + 128 + k] = 1.0f;
    }
}

// ---------------- main: split-K MFMA GEMM, DMA-staged B --------------------
template<int NSLABS>
static __device__ __forceinline__ void run_gemm(
    int nplanes, int p0, const unsigned short* asrc, int astride,
    const unsigned short* __restrict__ wt, unsigned short* __restrict__ slices,
    int chunk, int b0, int o0, int t,
    unsigned short (*B_lds)[64 * 64], float* h_s)
{
    const int lane = t & 63, wave = t >> 6;
    const int wm = wave >> 1, wn = wave & 1;
    const int qg = lane >> 4, ncol = lane & 15;

    // lane-constant DMA source pieces (swizzle folded into source gather)
    const int drow = lane >> 3;                  // 0..7
    const int dcol = ((lane & 7) ^ drow) * 8;    // swizzled k-block (shorts)

    // A fragments: loaded once, pure bf16 vector loads, all-static indexing
    bf16x8 xf[NSLABS][2][2];
    #pragma unroll
    for (int sl = 0; sl < NSLABS; ++sl)
        #pragma unroll
        for (int ks = 0; ks < 2; ++ks)
            #pragma unroll
            for (int mf = 0; mf < 2; ++mf)
                xf[sl][ks][mf] = *(const bf16x8*)(asrc
                    + (size_t)(b0 + wm * 32 + mf * 16 + ncol) * astride
                    + sl * 64 + ks * 32 + qg * 8);

    f32x4 acc[2][2] = {};
    f32x4 pacc[2][2];
    float hv[2][4];

    auto dmaB = [&](int plane, int i0, int buf) {
        const unsigned short* gp = wt + (size_t)plane * PLANE_SZ
            + (size_t)(o0 + wave * 16 + drow) * 256 + i0 + dcol;
        __builtin_amdgcn_global_load_lds(
            (const __attribute__((address_space(1))) unsigned int*)gp,
            (__attribute__((address_space(3))) unsigned int*)&B_lds[buf][wave * 16 * 64],
            16, 0, 0);
        __builtin_amdgcn_global_load_lds(
            (const __attribute__((address_space(1))) unsigned int*)(gp + 8 * 256),
            (__attribute__((address_space(3))) unsigned int*)&B_lds[buf][(wave * 16 + 8) * 64],
            16, 0, 0);
    };

    dmaB(p0, 0, 0);
    __syncthreads();

    for (int pl = 0; pl < nplanes; ++pl) {
        #pragma unroll
        for (int sl = 0; sl < NSLABS; ++sl) {
            const int buf = sl & 1;              // NSLABS even -> parity continuous
            if (sl + 1 < NSLABS)          dmaB(p0 + pl,     (sl + 1) * 64, buf ^ 1);
            else if (pl + 1 < nplanes)    dmaB(p0 + pl + 1, 0,             buf ^ 1);

            if (sl == 0) {
                #pragma unroll
                for (int mf = 0; mf < 2; ++mf)
                    #pragma unroll
                    for (int r = 0; r < 4; ++r)
                        hv[mf][r] = h_s[(wm * 32 + mf * 16 + qg * 4 + r) * 4 + pl];
                #pragma unroll
                for (int a = 0; a < 2; ++a)
                    #pragma unroll
                    for (int bq = 0; bq < 2; ++bq)
                        pacc[a][bq] = (f32x4){0.f, 0.f, 0.f, 0.f};
            }

            #pragma unroll
            for (int ks = 0; ks < 2; ++ks) {
                bf16x8 bfr[2];
                #pragma unroll
                for (int nf = 0; nf < 2; ++nf) {
                    int n = wn * 32 + nf * 16 + ncol;
                    bfr[nf] = *(const bf16x8*)&B_lds[buf][(n * 8 + ((ks * 4 + qg) ^ (n & 7))) * 8];
                }
                #pragma unroll
                for (int mf = 0; mf < 2; ++mf)
                    #pragma unroll
                    for (int nf = 0; nf < 2; ++nf)
                        pacc[mf][nf] = __builtin_amdgcn_mfma_f32_16x16x32_bf16(
                            xf[sl][ks][mf], bfr[nf], pacc[mf][nf], 0, 0, 0);
            }

            if (sl == NSLABS - 1) {              // fold plane into acc with h scale
                #pragma unroll
                for (int mf = 0; mf < 2; ++mf)
                    #pragma unroll
                    for (int nf = 0; nf < 2; ++nf)
                        #pragma unroll
                        for (int r = 0; r < 4; ++r)
                            acc[mf][nf][r] += hv[mf][r] * pacc[mf][nf][r];
            }
            __syncthreads();
        }
    }

    unsigned short* slice = slices + (size_t)chunk * OUT_ELEMS;
    #pragma unroll
    for (int mf = 0; mf < 2; ++mf)
        #pragma unroll
        for (int nf = 0; nf < 2; ++nf)
            #pragma unroll
            for (int r = 0; r < 4; ++r) {
                int row = b0 + wm * 32 + mf * 16 + qg * 4 + r;
                int col = o0 + wn * 32 + nf * 16 + ncol;
                slice[(size_t)row * OUT_DIM + col] = f2bf(acc[mf][nf][r]);
            }
}

__global__ __launch_bounds__(256, 3)
void hyper_main_kernel(const unsigned short* __restrict__ wt,
                       unsigned short* __restrict__ slices) {
    __shared__ __align__(16) unsigned short B_lds[2][64 * 64];   // 16 KB
    __shared__ float h_s[256];

    const int bx    = blockIdx.x;            // 34 * 32
    const int chunk = bx >> 5;
    const int rem   = bx & 31;
    const int b0    = (rem >> 2) * 64;
    const int o0    = (rem & 3) * 64;
    const int t     = threadIdx.x;

    int p0 = (chunk < 32) ? chunk * 4 : (chunk == 32 ? 128 : 130);

    // stage per-plane h scales (chunk 32/33 rows read 1.0 from g_h ones-lanes)
    h_s[t] = g_h[(b0 + (t >> 2)) * H_STRIDE + p0 + (t & 3)];

    if (chunk < 33)
        run_gemm<4>(chunk < 32 ? 4 : 2, p0, g_xbf, IN_DIM,
                    wt, slices, chunk, b0, o0, t, B_lds, h_s);
    else
        run_gemm<2>(1, p0, g_hbf, HIDDEN,
                    wt, slices, chunk, b0, o0, t, B_lds, h_s);
}

// ---------------- reduce: sum bf16 slices + bias vectors -------------------
__global__ void hyper_reduce_kernel(const unsigned short* __restrict__ slices,
                                    const float* __restrict__ base_bias,
                                    const float* __restrict__ b2,
                                    float* __restrict__ out) {
    int i = blockIdx.x * 256 + threadIdx.x;        // float4 index, 32768 total
    int o = (i & 63) * 4;
    float4 bb = *(const float4*)(base_bias + o);
    float4 c2 = *(const float4*)(b2 + 65536 + o);
    float4 a;
    a.x = bb.x + c2.x; a.y = bb.y + c2.y; a.z = bb.z + c2.z; a.w = bb.w + c2.w;
    #pragma unroll
    for (int c = 0; c < NCHUNKS; ++c) {
        ushort4 v = *(const ushort4*)(slices + (size_t)c * OUT_ELEMS + (size_t)i * 4);
        a.x += bf2f(v.x); a.y += bf2f(v.y); a.z += bf2f(v.z); a.w += bf2f(v.w);
    }
    ((float4*)out)[i] = a;
}

// ---------------- launch ---------------------------------------------------
extern "C" void kernel_launch(void* const* d_in, const int* in_sizes, int n_in,
                              void* d_out, int out_size, void* d_ws, size_t ws_size,
                              hipStream_t stream) {
    const float* x           = (const float*)d_in[0];
    const float* cond        = (const float*)d_in[1];
    const float* base_weight = (const float*)d_in[2];
    const float* base_bias   = (const float*)d_in[3];
    const float* w1          = (const float*)d_in[4];
    const float* b1          = (const float*)d_in[5];
    const float* w2          = (const float*)d_in[6];
    const float* b2          = (const float*)d_in[7];
    float* out = (float*)d_out;
    unsigned short* ws = (unsigned short*)d_ws;     // 131 planes + 34 slices = 26.1 MB

    hyper_prep_kernel<<<2360, 256, 0, stream>>>(x, cond, base_weight, w1, b1, w2, b2, ws);
    hyper_main_kernel<<<NCHUNKS * 32, 256, 0, stream>>>(ws, ws + SLICE_OFF);
    hyper_reduce_kernel<<<OUT_ELEMS / 4 / 256, 256, 0, stream>>>(ws + SLICE_OFF, base_bias, b2, out);
}